// Round 10
// baseline (201.118 us; speedup 1.0000x reference)
//
#include <hip/hip_runtime.h>
#include <hip/hip_bf16.h>

typedef __bf16 bf16;
typedef bf16 bf16x8 __attribute__((ext_vector_type(8)));
typedef bf16 bf16x4 __attribute__((ext_vector_type(4)));
typedef float f32x4 __attribute__((ext_vector_type(4)));
typedef float f32x16 __attribute__((ext_vector_type(16)));
typedef unsigned short ushortT;
typedef ushortT ushort8 __attribute__((ext_vector_type(8)));

#define DEV __device__ __forceinline__

constexpr int DMODEL = 1024;
constexpr int NH = 16;
constexpr int DK = 64;
constexpr int SEQ = 2048;
constexpr int BATCH = 4;
constexpr int MROWS = BATCH * SEQ;   // 8192
constexpr int KDIM = 1024;

#define GLOAD_LDS16(g, l) __builtin_amdgcn_global_load_lds( \
    (const __attribute__((address_space(1))) void*)(g), \
    (__attribute__((address_space(3))) void*)(l), 16, 0, 0)

// counted-vmcnt pipeline wait: only the OLDEST loads must have landed; newer
// prefetches stay in flight across the barrier (T4).
#define PIPE_WAIT(N) do { \
    __builtin_amdgcn_sched_barrier(0); \
    asm volatile("s_waitcnt vmcnt(" #N ")" ::: "memory"); \
    __builtin_amdgcn_s_barrier(); \
    __builtin_amdgcn_sched_barrier(0); \
} while (0)

// ---------------- f32 -> bf16 conversion ----------------
__global__ void cvt_bf16(const float* __restrict__ src, bf16* __restrict__ dst, int n) {
    int i = (blockIdx.x * blockDim.x + threadIdx.x) * 8;
    if (i >= n) return;
    float4 f0 = *reinterpret_cast<const float4*>(src + i);
    float4 f1 = *reinterpret_cast<const float4*>(src + i + 4);
    bf16x8 o;
    o[0] = (bf16)f0.x; o[1] = (bf16)f0.y; o[2] = (bf16)f0.z; o[3] = (bf16)f0.w;
    o[4] = (bf16)f1.x; o[5] = (bf16)f1.y; o[6] = (bf16)f1.z; o[7] = (bf16)f1.w;
    *reinterpret_cast<bf16x8*>(dst + i) = o;
}

// all four weight matrices in one launch (grid.y selects)
__global__ void cvt_bf16_w(const float* __restrict__ s0, const float* __restrict__ s1,
                           const float* __restrict__ s2, const float* __restrict__ s3,
                           bf16* __restrict__ d0, bf16* __restrict__ d1,
                           bf16* __restrict__ d2, bf16* __restrict__ d3) {
    int which = blockIdx.y;
    const float* s = which == 0 ? s0 : which == 1 ? s1 : which == 2 ? s2 : s3;
    bf16* d = which == 0 ? d0 : which == 1 ? d1 : which == 2 ? d2 : d3;
    int i = (blockIdx.x * blockDim.x + threadIdx.x) * 8;
    float4 f0 = *reinterpret_cast<const float4*>(s + i);
    float4 f1 = *reinterpret_cast<const float4*>(s + i + 4);
    bf16x8 o;
    o[0] = (bf16)f0.x; o[1] = (bf16)f0.y; o[2] = (bf16)f0.z; o[3] = (bf16)f0.w;
    o[4] = (bf16)f1.x; o[5] = (bf16)f1.y; o[6] = (bf16)f1.z; o[7] = (bf16)f1.w;
    *reinterpret_cast<bf16x8*>(d + i) = o;
}

// ---------------- RoPE table: interleaved (cos,sin) pairs ----------------
__global__ void rope_tab(float2* __restrict__ csT) {
    int i = blockIdx.x * blockDim.x + threadIdx.x;  // [0, 2048*32)
    int p = i >> 5, k = i & 31;
    float inv = powf(10000.0f, -2.0f * (float)k / 64.0f);
    float ang = (float)p * inv;
    csT[i] = make_float2(cosf(ang), sinf(ang));
}

// ---------------- QKV GEMM, swapped operands (C^T = W X^T), RoPE lane-local ----------
// 4-buffer BK=32 pipeline, 3-deep prefetch, counted vmcnt(8) (T3+T4), setprio (T5).
// LDS tile [64 rows x 8 slots of 16B]: tile-row tr -> LDS row tr&63, logical slot
// (tr>>6)*4 + lg, phys slot = logical ^ (row&7) (T2 swizzle, staged via
// pre-permuted global source so global_load_lds dest stays linear).
__global__ __launch_bounds__(256) void gemm_qkv(
    const bf16* __restrict__ Xb,
    const bf16* __restrict__ Wqb, const bf16* __restrict__ Wkb, const bf16* __restrict__ Wvb,
    bf16* __restrict__ Qb, bf16* __restrict__ Kb, bf16* __restrict__ Vb,
    const int* __restrict__ tokpos, const float2* __restrict__ csT)
{
    __shared__ bf16 As[4][64 * 64];   // X rows (s), 8KB per buffer
    __shared__ bf16 Bs[4][64 * 64];   // W rows (d)

    const int which = blockIdx.z;
    const bf16* Bmat = which == 0 ? Wqb : (which == 1 ? Wkb : Wvb);
    bf16* Out = which == 0 ? Qb : (which == 1 ? Kb : Vb);

    const int m0 = blockIdx.x * 128;   // s tile
    const int n0 = blockIdx.y * 128;   // d tile
    const int t = threadIdx.x;
    const int w = t >> 6, l = t & 63;
    const int wd = w >> 1, ws = w & 1;   // wave quadrant: d-half, s-half
    const int lm = l & 15, lg = l >> 4;
    // staging lane geometry: LDS row R = ci*8 + (l>>3), phys slot l&7;
    // logical lgc = (l&7)^(l>>3): tile-row = R + 64*(lgc>>2), k-seg = lgc&3
    const int lr = l >> 3, sE = l & 7;
    const int lgc = sE ^ lr;
    const int trO = lr + ((lgc >> 2) << 6);
    const int kO = (lgc & 3) * 8;
    // fragment-read swizzled slots
    const int slA = (((ws * 4 + lg) ^ (lm & 7)) * 8);
    const int slB = (((wd * 4 + lg) ^ (lm & 7)) * 8);

    f32x4 acc[4][4] = {};   // [ni (d)][mi (s)]

    auto stage = [&](int kt, int kb) {
#pragma unroll
        for (int c = 0; c < 2; ++c) {
            const int ci = c * 4 + w;   // 0..7
            GLOAD_LDS16(Xb + (size_t)(m0 + ci * 8 + trO) * KDIM + kt + kO, &As[kb][ci * 512]);
            GLOAD_LDS16(Bmat + (size_t)(n0 + ci * 8 + trO) * KDIM + kt + kO, &Bs[kb][ci * 512]);
        }
    };

    auto compute = [&](int kb) {
        bf16x8 wf[4], xf[4];
#pragma unroll
        for (int ni = 0; ni < 4; ++ni)
            wf[ni] = *reinterpret_cast<const bf16x8*>(&Bs[kb][(ni * 16 + lm) * 64 + slB]);
#pragma unroll
        for (int mi = 0; mi < 4; ++mi)
            xf[mi] = *reinterpret_cast<const bf16x8*>(&As[kb][(mi * 16 + lm) * 64 + slA]);
        __builtin_amdgcn_s_setprio(1);
#pragma unroll
        for (int ni = 0; ni < 4; ++ni)
#pragma unroll
            for (int mi = 0; mi < 4; ++mi)
                acc[ni][mi] = __builtin_amdgcn_mfma_f32_16x16x32_bf16(wf[ni], xf[mi], acc[ni][mi], 0, 0, 0);
        __builtin_amdgcn_s_setprio(0);
    };

    stage(0, 0);
    stage(32, 1);
    stage(64, 2);
    PIPE_WAIT(8);                       // tile0 landed; 1,2 in flight
    for (int it = 0; it < 29; ++it) {
        stage(it * 32 + 96, (it + 3) & 3);
        compute(it & 3);
        PIPE_WAIT(8);                   // tile it+1 landed; it+2, it+3 in flight
    }
    compute(1); PIPE_WAIT(4);           // it=29: tile 30 landed, 31 in flight
    compute(2); PIPE_WAIT(0);           // it=30: tile 31 landed
    compute(3);                         // it=31

    // epilogue: lane-local RoPE + vectorized scatter to [B,H,S,DK]
    const int h = (int)blockIdx.y * 2 + wd;   // head index
#pragma unroll
    for (int mi = 0; mi < 4; ++mi) {
        const int rowg = m0 + ws * 64 + mi * 16 + lm;  // global token row
        const int b = rowg >> 11, ss = rowg & 2047;
        const size_t obase = ((size_t)(b * NH + h) * SEQ + ss) * DK;
        int p = 0;
        if (which < 2) p = tokpos[rowg];
#pragma unroll
        for (int ni = 0; ni < 4; ++ni) {
            const int dloc = ni * 16 + lg * 4;   // within-head d, multiple of 4
            f32x4 a = acc[ni][mi];
            bf16x4 v4;
            if (which < 2) {
                const int k2 = dloc >> 1;
                float2 cs0 = csT[p * 32 + k2];
                float2 cs1 = csT[p * 32 + k2 + 1];
                v4[0] = (bf16)(a[0] * cs0.x - a[1] * cs0.y);
                v4[1] = (bf16)(a[0] * cs0.y + a[1] * cs0.x);
                v4[2] = (bf16)(a[2] * cs1.x - a[3] * cs1.y);
                v4[3] = (bf16)(a[2] * cs1.y + a[3] * cs1.x);
            } else {
                v4[0] = (bf16)a[0]; v4[1] = (bf16)a[1];
                v4[2] = (bf16)a[2]; v4[3] = (bf16)a[3];
            }
            *reinterpret_cast<bf16x4*>(Out + obase + dloc) = v4;
        }
    }
}

// ---------------- V transpose [B,H,S,DK] -> [B,H,DK,S], sigma-permuted kv order ----
// Within each 32-kv group, position p holds kv = 16*(p>>4) + 4*((p>>3)&1) + (p&3) + 8*((p>>2)&1)
// -> per 16-group, dst = src reordered {0-3, 8-11, 4-7, 12-15}.
__global__ void vtrans(const bf16* __restrict__ Vb, bf16* __restrict__ Vt) {
    __shared__ ushortT tile[64][66];
    int bh = blockIdx.y, st = blockIdx.x;
    int t = threadIdx.x;
    int r = t >> 2, c4 = (t & 3) * 16;
    const ushortT* src = (const ushortT*)(Vb + ((size_t)bh * SEQ + st * 64 + r) * DK + c4);
    *reinterpret_cast<ushort8*>(&tile[r][c4]) = *reinterpret_cast<const ushort8*>(src);
    *reinterpret_cast<ushort8*>(&tile[r][c4 + 8]) = *reinterpret_cast<const ushort8*>(src + 8);
    __syncthreads();
    ushortT a[16];
#pragma unroll
    for (int i = 0; i < 16; ++i) a[i] = tile[c4 + i][r];
    ushort8 n0, n1;
#pragma unroll
    for (int i = 0; i < 4; ++i) {
        n0[i] = a[i];       n0[4 + i] = a[8 + i];
        n1[i] = a[4 + i];   n1[4 + i] = a[12 + i];
    }
    ushortT* dst = (ushortT*)(Vt + ((size_t)bh * DK + r) * SEQ + st * 64 + c4);
    *reinterpret_cast<ushort8*>(dst) = n0;
    *reinterpret_cast<ushort8*>(dst + 8) = n1;
}

// ---------------- flash attention (causal), LDS-staged K/V, 32x32 MFMA ----------------
constexpr float CL = 0.18033688011112042f;  // 0.125 * log2(e)
constexpr float THR = 64.0f;                // defer-max threshold (raw units; 8 post-scale)

template<int MODE>  // 0: chunks 0+1 unmasked; 1: chunks 0+1 masked; 2: chunk0 only, masked
DEV void tileproc(const bf16* __restrict__ Klb, const bf16* __restrict__ Vlb,
                  int kv0, int q_abs, int ql, int hi, int swq,
                  const bf16x8 qb[4], f32x16 o[2], float& lsum, float& mrow)
{
    f32x16 s0 = {}, s1 = {};
#pragma unroll
    for (int sl = 0; sl < 4; ++sl) {
        bf16x8 k0 = *reinterpret_cast<const bf16x8*>(&Klb[ql * 64 + (((sl * 2 + hi) ^ swq) * 8)]);
        s0 = __builtin_amdgcn_mfma_f32_32x32x16_bf16(k0, qb[sl], s0, 0, 0, 0);
        if (MODE != 2) {
            bf16x8 k1 = *reinterpret_cast<const bf16x8*>(&Klb[(32 + ql) * 64 + (((sl * 2 + hi) ^ swq) * 8)]);
            s1 = __builtin_amdgcn_mfma_f32_32x32x16_bf16(k1, qb[sl], s1, 0, 0, 0);
        }
    }

    if (MODE >= 1) {
#pragma unroll
        for (int r = 0; r < 16; ++r) {
            const int kvl = (r & 3) + 8 * (r >> 2) + 4 * hi;
            if (kv0 + kvl > q_abs) s0[r] = -1e30f;
            if (MODE == 1 && kv0 + 32 + kvl > q_abs) s1[r] = -1e30f;
        }
    }

    // joint row max (lane-local tree + 1 cross-half shuffle)
    f32x16 mm = s0;
    if (MODE != 2) {
#pragma unroll
        for (int r = 0; r < 16; ++r) mm[r] = fmaxf(mm[r], s1[r]);
    }
    float m0 = fmaxf(fmaxf(mm[0], mm[1]), fmaxf(mm[2], mm[3]));
    float m1 = fmaxf(fmaxf(mm[4], mm[5]), fmaxf(mm[6], mm[7]));
    float m2 = fmaxf(fmaxf(mm[8], mm[9]), fmaxf(mm[10], mm[11]));
    float m3 = fmaxf(fmaxf(mm[12], mm[13]), fmaxf(mm[14], mm[15]));
    float pmax = fmaxf(fmaxf(m0, m1), fmaxf(m2, m3));
    pmax = fmaxf(pmax, __shfl_xor(pmax, 32));

    if (!__all(pmax <= mrow + THR)) {
        const float mnew = fmaxf(mrow, pmax);
        const float alpha = __builtin_amdgcn_exp2f((mrow - mnew) * CL);
        mrow = mnew;
        lsum *= alpha;
        o[0] *= alpha;
        o[1] *= alpha;
    }

#pragma unroll
    for (int r = 0; r < 16; ++r) {
        s0[r] = __builtin_amdgcn_exp2f((s0[r] - mrow) * CL);
        if (MODE != 2) s1[r] = __builtin_amdgcn_exp2f((s1[r] - mrow) * CL);
    }
    {
        float a0 = (s0[0] + s0[1]) + (s0[2] + s0[3]);
        float a1 = (s0[4] + s0[5]) + (s0[6] + s0[7]);
        float a2 = (s0[8] + s0[9]) + (s0[10] + s0[11]);
        float a3 = (s0[12] + s0[13]) + (s0[14] + s0[15]);
        float ps = (a0 + a1) + (a2 + a3);
        if (MODE != 2) {
            float b0 = (s1[0] + s1[1]) + (s1[2] + s1[3]);
            float b1 = (s1[4] + s1[5]) + (s1[6] + s1[7]);
            float b2 = (s1[8] + s1[9]) + (s1[10] + s1[11]);
            float b3 = (s1[12] + s1[13]) + (s1[14] + s1[15]);
            ps += (b0 + b1) + (b2 + b3);
        }
        lsum += ps;
    }

    // PV: O^T += V^T-frag x P^T-frag; pb lane-local repack, va contiguous b128 reads
#pragma unroll
    for (int c = 0; c < (MODE == 2 ? 1 : 2); ++c) {
#pragma unroll
        for (int u2 = 0; u2 < 2; ++u2) {
            const int u = c * 2 + u2;
            bf16x8 pb;
#pragma unroll
            for (int j = 0; j < 8; ++j) pb[j] = (bf16)(c ? s1[u2 * 8 + j] : s0[u2 * 8 + j]);
#pragma unroll
            for (int dt = 0; dt < 2; ++dt) {
                bf16x8 va = *reinterpret_cast<const bf16x8*>(
                    &Vlb[(dt * 32 + ql) * 64 + (((u * 2 + hi) ^ swq) * 8)]);
                o[dt] = __builtin_amdgcn_mfma_f32_32x32x16_bf16(va, pb, o[dt], 0, 0, 0);
            }
        }
    }
}

__global__ __launch_bounds__(256, 3) void attn(
    const bf16* __restrict__ Qb, const bf16* __restrict__ Kb, const bf16* __restrict__ Vt,
    bf16* __restrict__ Ab)
{
    __shared__ bf16 Kl[2][64 * 64];
    __shared__ bf16 Vl[2][64 * 64];

    const int bh = blockIdx.x;
    const int qt = (int)gridDim.y - 1 - (int)blockIdx.y;   // longest tiles launch first (LPT)
    const int t = threadIdx.x, w = t >> 6, l = t & 63;
    const int ql = l & 31, hi = l >> 5;
    const int q0 = qt * 128 + w * 32;
    const bf16* Qh = Qb + (size_t)bh * SEQ * DK;
    const bf16* Kh = Kb + (size_t)bh * SEQ * DK;
    const bf16* Vh = Vt + (size_t)bh * DK * SEQ;

    // staging geometry: per wave-call, lane l covers LDS row w*8 + (l>>3), slot l&7 (16B)
    const int lr = l >> 3, slot = l & 7;
    const int sw8 = ((slot ^ lr) * 8);         // pre-swizzled source column (elements)
    const int r0 = w * 8 + lr;

    auto stage = [&](int tile, int buf) {
        const int kv0 = tile * 64;
        GLOAD_LDS16(Kh + (size_t)(kv0 + r0) * DK + sw8,       &Kl[buf][w * 512]);
        GLOAD_LDS16(Kh + (size_t)(kv0 + 32 + r0) * DK + sw8,  &Kl[buf][2048 + w * 512]);
        GLOAD_LDS16(Vh + (size_t)r0 * SEQ + kv0 + sw8,        &Vl[buf][w * 512]);
        GLOAD_LDS16(Vh + (size_t)(32 + r0) * SEQ + kv0 + sw8, &Vl[buf][2048 + w * 512]);
    };

    bf16x8 qb[4];
#pragma unroll
    for (int sl = 0; sl < 4; ++sl)
        qb[sl] = *reinterpret_cast<const bf16x8*>(Qh + (size_t)(q0 + ql) * DK + sl * 16 + hi * 8);

    f32x16 o[2] = {};
    float lsum = 0.0f;
    float mrow = -1e30f;
    const int q_abs = q0 + ql;
    const int swq = ql & 7;

    const int ntile = 2 * qt + 2;
    stage(0, 0);
    __syncthreads();
    for (int tt = 0; tt < ntile; ++tt) {
        if (tt + 1 < ntile) stage(tt + 1, (tt + 1) & 1);
        const int kv0 = tt * 64;
        const bf16* Klb = &Kl[tt & 1][0];
        const bf16* Vlb = &Vl[tt & 1][0];
        if (tt < 2 * qt) {
            tileproc<0>(Klb, Vlb, kv0, q_abs, ql, hi, swq, qb, o, lsum, mrow);
        } else {
            const bool a0 = kv0 <= q0 + 31;
            const bool a1 = kv0 + 32 <= q0 + 31;
            if (a1)      tileproc<1>(Klb, Vlb, kv0, q_abs, ql, hi, swq, qb, o, lsum, mrow);
            else if (a0) tileproc<2>(Klb, Vlb, kv0, q_abs, ql, hi, swq, qb, o, lsum, mrow);
        }
        __syncthreads();
    }

    // cross-half sum, lane-local normalize + store
    const float rs = lsum + __shfl_xor(lsum, 32);
    const float rinv = 1.0f / rs;

    const int b = bh >> 4, h = bh & 15;
    const int q = q0 + ql;
    const size_t rowbase = ((size_t)(b * SEQ + q)) * DMODEL + h * 64;
#pragma unroll
    for (int dt = 0; dt < 2; ++dt)
#pragma unroll
        for (int g = 0; g < 4; ++g) {
            bf16x4 v4;
#pragma unroll
            for (int e = 0; e < 4; ++e) v4[e] = (bf16)(o[dt][4 * g + e] * rinv);
            *reinterpret_cast<bf16x4*>(Ab + rowbase + dt * 32 + 8 * g + 4 * hi) = v4;
        }
}

// ---------------- output GEMM, swapped operands (C^T = Wo Ab^T), float4 stores ------
// Same 4-buffer counted-vmcnt pipeline as gemm_qkv.
__global__ __launch_bounds__(256) void gemm_out(
    const bf16* __restrict__ Ab, const bf16* __restrict__ Wob, float* __restrict__ Out)
{
    __shared__ bf16 As[4][64 * 64];
    __shared__ bf16 Bs[4][64 * 64];

    const int m0 = blockIdx.x * 128;
    const int n0 = blockIdx.y * 128;
    const int t = threadIdx.x;
    const int w = t >> 6, l = t & 63;
    const int wd = w >> 1, ws = w & 1;
    const int lm = l & 15, lg = l >> 4;
    const int lr = l >> 3, sE = l & 7;
    const int lgc = sE ^ lr;
    const int trO = lr + ((lgc >> 2) << 6);
    const int kO = (lgc & 3) * 8;
    const int slA = (((ws * 4 + lg) ^ (lm & 7)) * 8);
    const int slB = (((wd * 4 + lg) ^ (lm & 7)) * 8);

    f32x4 acc[4][4] = {};   // [ni (n)][mi (s)]

    auto stage = [&](int kt, int kb) {
#pragma unroll
        for (int c = 0; c < 2; ++c) {
            const int ci = c * 4 + w;
            GLOAD_LDS16(Ab + (size_t)(m0 + ci * 8 + trO) * KDIM + kt + kO, &As[kb][ci * 512]);
            GLOAD_LDS16(Wob + (size_t)(n0 + ci * 8 + trO) * KDIM + kt + kO, &Bs[kb][ci * 512]);
        }
    };

    auto compute = [&](int kb) {
        bf16x8 wf[4], xf[4];
#pragma unroll
        for (int ni = 0; ni < 4; ++ni)
            wf[ni] = *reinterpret_cast<const bf16x8*>(&Bs[kb][(ni * 16 + lm) * 64 + slB]);
#pragma unroll
        for (int mi = 0; mi < 4; ++mi)
            xf[mi] = *reinterpret_cast<const bf16x8*>(&As[kb][(mi * 16 + lm) * 64 + slA]);
        __builtin_amdgcn_s_setprio(1);
#pragma unroll
        for (int ni = 0; ni < 4; ++ni)
#pragma unroll
            for (int mi = 0; mi < 4; ++mi)
                acc[ni][mi] = __builtin_amdgcn_mfma_f32_16x16x32_bf16(wf[ni], xf[mi], acc[ni][mi], 0, 0, 0);
        __builtin_amdgcn_s_setprio(0);
    };

    stage(0, 0);
    stage(32, 1);
    stage(64, 2);
    PIPE_WAIT(8);
    for (int it = 0; it < 29; ++it) {
        stage(it * 32 + 96, (it + 3) & 3);
        compute(it & 3);
        PIPE_WAIT(8);
    }
    compute(1); PIPE_WAIT(4);
    compute(2); PIPE_WAIT(0);
    compute(3);

#pragma unroll
    for (int mi = 0; mi < 4; ++mi) {
        const int rowg = m0 + ws * 64 + mi * 16 + lm;
#pragma unroll
        for (int ni = 0; ni < 4; ++ni) {
            const int ncol = n0 + wd * 64 + ni * 16 + lg * 4;
            *reinterpret_cast<f32x4*>(Out + (size_t)rowg * DMODEL + ncol) = acc[ni][mi];
        }
    }
}

// ---------------- launch ----------------
extern "C" void kernel_launch(void* const* d_in, const int* in_sizes, int n_in,
                              void* d_out, int out_size, void* d_ws, size_t ws_size,
                              hipStream_t stream) {
    const float* X  = (const float*)d_in[0];
    const int* tokpos = (const int*)d_in[1];
    const float* Wq = (const float*)d_in[2];
    const float* Wk = (const float*)d_in[3];
    const float* Wv = (const float*)d_in[4];
    const float* Wo = (const float*)d_in[5];

    char* ws = (char*)d_ws;
    bf16* Xb  = (bf16*)(ws + 0);            // 16 MB
    bf16* Wqb = (bf16*)(ws + 16777216);     // 2 MB
    bf16* Wkb = (bf16*)(ws + 18874368);
    bf16* Wvb = (bf16*)(ws + 20971520);
    bf16* Wob = (bf16*)(ws + 23068672);
    float2* csT = (float2*)(ws + 25165824); // 512 KB interleaved (cos,sin)
    bf16* Qb = (bf16*)(ws + 25690112);      // 16 MB
    bf16* Kb = (bf16*)(ws + 42467328);
    bf16* Vb = (bf16*)(ws + 59244544);
    bf16* Vt = (bf16*)(ws + 76021760);
    bf16* Ab = (bf16*)(ws + 92798976);      // ends at 109,576,192

    cvt_bf16<<<4096, 256, 0, stream>>>(X, Xb, MROWS * DMODEL);
    cvt_bf16_w<<<dim3(512, 4), 256, 0, stream>>>(Wq, Wk, Wv, Wo, Wqb, Wkb, Wvb, Wob);
    rope_tab<<<256, 256, 0, stream>>>(csT);

    gemm_qkv<<<dim3(MROWS / 128, DMODEL / 128, 3), 256, 0, stream>>>(
        Xb, Wqb, Wkb, Wvb, Qb, Kb, Vb, tokpos, csT);

    vtrans<<<dim3(SEQ / 64, BATCH * NH), 256, 0, stream>>>(Vb, Vt);

    attn<<<dim3(BATCH * NH, SEQ / 128), 256, 0, stream>>>(Qb, Kb, Vt, Ab);

    gemm_out<<<dim3(MROWS / 128, DMODEL / 128), 256, 0, stream>>>(Ab, Wob, (float*)d_out);
}

// Round 11
// 186.099 us; speedup vs baseline: 1.0807x; 1.0807x over previous
//
#include <hip/hip_runtime.h>
#include <hip/hip_bf16.h>

typedef __bf16 bf16;
typedef bf16 bf16x8 __attribute__((ext_vector_type(8)));
typedef bf16 bf16x4 __attribute__((ext_vector_type(4)));
typedef float f32x4 __attribute__((ext_vector_type(4)));
typedef float f32x16 __attribute__((ext_vector_type(16)));
typedef unsigned short ushortT;
typedef ushortT ushort8 __attribute__((ext_vector_type(8)));

#define DEV __device__ __forceinline__

constexpr int DMODEL = 1024;
constexpr int NH = 16;
constexpr int DK = 64;
constexpr int SEQ = 2048;
constexpr int BATCH = 4;
constexpr int MROWS = BATCH * SEQ;   // 8192
constexpr int KDIM = 1024;

#define GLOAD_LDS16(g, l) __builtin_amdgcn_global_load_lds( \
    (const __attribute__((address_space(1))) void*)(g), \
    (__attribute__((address_space(3))) void*)(l), 16, 0, 0)

#define PIPE_WAIT(N) do { \
    __builtin_amdgcn_sched_barrier(0); \
    asm volatile("s_waitcnt vmcnt(" #N ")" ::: "memory"); \
    __builtin_amdgcn_s_barrier(); \
    __builtin_amdgcn_sched_barrier(0); \
} while (0)

// ---------------- f32 -> bf16 conversion ----------------
__global__ void cvt_bf16(const float* __restrict__ src, bf16* __restrict__ dst, int n) {
    int i = (blockIdx.x * blockDim.x + threadIdx.x) * 8;
    if (i >= n) return;
    float4 f0 = *reinterpret_cast<const float4*>(src + i);
    float4 f1 = *reinterpret_cast<const float4*>(src + i + 4);
    bf16x8 o;
    o[0] = (bf16)f0.x; o[1] = (bf16)f0.y; o[2] = (bf16)f0.z; o[3] = (bf16)f0.w;
    o[4] = (bf16)f1.x; o[5] = (bf16)f1.y; o[6] = (bf16)f1.z; o[7] = (bf16)f1.w;
    *reinterpret_cast<bf16x8*>(dst + i) = o;
}

// all four weight matrices in one launch (grid.y selects)
__global__ void cvt_bf16_w(const float* __restrict__ s0, const float* __restrict__ s1,
                           const float* __restrict__ s2, const float* __restrict__ s3,
                           bf16* __restrict__ d0, bf16* __restrict__ d1,
                           bf16* __restrict__ d2, bf16* __restrict__ d3) {
    int which = blockIdx.y;
    const float* s = which == 0 ? s0 : which == 1 ? s1 : which == 2 ? s2 : s3;
    bf16* d = which == 0 ? d0 : which == 1 ? d1 : which == 2 ? d2 : d3;
    int i = (blockIdx.x * blockDim.x + threadIdx.x) * 8;
    float4 f0 = *reinterpret_cast<const float4*>(s + i);
    float4 f1 = *reinterpret_cast<const float4*>(s + i + 4);
    bf16x8 o;
    o[0] = (bf16)f0.x; o[1] = (bf16)f0.y; o[2] = (bf16)f0.z; o[3] = (bf16)f0.w;
    o[4] = (bf16)f1.x; o[5] = (bf16)f1.y; o[6] = (bf16)f1.z; o[7] = (bf16)f1.w;
    *reinterpret_cast<bf16x8*>(d + i) = o;
}

// ---------------- RoPE table: interleaved (cos,sin) pairs ----------------
__global__ void rope_tab(float2* __restrict__ csT) {
    int i = blockIdx.x * blockDim.x + threadIdx.x;  // [0, 2048*32)
    int p = i >> 5, k = i & 31;
    float inv = powf(10000.0f, -2.0f * (float)k / 64.0f);
    float ang = (float)p * inv;
    csT[i] = make_float2(cosf(ang), sinf(ang));
}

// ---------------- QKV GEMM (C^T = W X^T), 8-wave 128d x 256s tile, BK=64 ----------
// Counted-vmcnt pipeline (provable, in-order vmcnt): W 2-buf staged 1 ahead,
// X 3-buf staged 2 ahead; per tile: issue [W(t+1), X(t+2)], compute, vmcnt(4)+barrier.
// At end-of-t queue = [X(t+1):4, W(t+1):2, X(t+2):4] -> vmcnt(4) lands all but X(t+2).
// T2 XOR swizzle via pre-swizzled global source; T5 setprio around MFMA cluster.
__global__ __launch_bounds__(512, 2) void gemm_qkv(
    const bf16* __restrict__ Xb,
    const bf16* __restrict__ Wqb, const bf16* __restrict__ Wkb, const bf16* __restrict__ Wvb,
    bf16* __restrict__ Qb, bf16* __restrict__ Kb, bf16* __restrict__ Vb,
    const int* __restrict__ tokpos, const float2* __restrict__ csT)
{
    __shared__ bf16 Wl[2][128 * 64];   // 2 x 16KB
    __shared__ bf16 Xl[3][256 * 64];   // 3 x 32KB  (total 128KB)

    const int which = (int)blockIdx.x >> 3;
    const bf16* Wmat = which == 0 ? Wqb : (which == 1 ? Wkb : Wvb);
    bf16* Out = which == 0 ? Qb : (which == 1 ? Kb : Vb);

    const int d0 = ((int)blockIdx.x & 7) * 128;  // d-tile within 1024
    const int s0 = (int)blockIdx.y * 256;        // token-row tile
    const int t = threadIdx.x;                   // 0..511
    const int w = t >> 6, l = t & 63;
    const int wd = w >> 2, wq = w & 3;           // wave quadrant: d-half, s-quarter
    const int lm = l & 15, lg = l >> 4;
    const int lm7 = lm & 7;
    const int slW = (((0 * 4 + lg)) * 0);        // (placeholder removed below)

    f32x4 acc[4][4] = {};   // [fi (d)][fj (s)]

    auto stageW = [&](int kt, int buf) {
#pragma unroll
        for (int j = 0; j < 2; ++j) {
            const int slot = w * 64 + j * 512 + l;   // per-lane, for source addr
            const int row = slot >> 3;
            const int col = ((slot & 7) ^ (row & 7)) * 8;
            GLOAD_LDS16(Wmat + (size_t)(d0 + row) * KDIM + kt + col,
                        &Wl[buf][(w * 64 + j * 512) * 8]);   // wave-uniform dest
        }
    };
    auto stageX = [&](int kt, int buf) {
#pragma unroll
        for (int j = 0; j < 4; ++j) {
            const int slot = w * 64 + j * 512 + l;
            const int row = slot >> 3;
            const int col = ((slot & 7) ^ (row & 7)) * 8;
            GLOAD_LDS16(Xb + (size_t)(s0 + row) * KDIM + kt + col,
                        &Xl[buf][(w * 64 + j * 512) * 8]);
        }
    };
    auto compute = [&](const bf16* Wb, const bf16* Xq) {
        bf16x8 wf[4][2], xf[4][2];
#pragma unroll
        for (int fi = 0; fi < 4; ++fi) {
            const int row = wd * 64 + fi * 16 + lm;
#pragma unroll
            for (int kk = 0; kk < 2; ++kk)
                wf[fi][kk] = *reinterpret_cast<const bf16x8*>(
                    Wb + row * 64 + (((kk * 4 + lg) ^ lm7) * 8));
        }
#pragma unroll
        for (int fj = 0; fj < 4; ++fj) {
            const int row = wq * 64 + fj * 16 + lm;
#pragma unroll
            for (int kk = 0; kk < 2; ++kk)
                xf[fj][kk] = *reinterpret_cast<const bf16x8*>(
                    Xq + row * 64 + (((kk * 4 + lg) ^ lm7) * 8));
        }
        __builtin_amdgcn_s_setprio(1);
#pragma unroll
        for (int kk = 0; kk < 2; ++kk)
#pragma unroll
            for (int fi = 0; fi < 4; ++fi)
#pragma unroll
                for (int fj = 0; fj < 4; ++fj)
                    acc[fi][fj] = __builtin_amdgcn_mfma_f32_16x16x32_bf16(
                        wf[fi][kk], xf[fj][kk], acc[fi][fj], 0, 0, 0);
        __builtin_amdgcn_s_setprio(0);
    };

    // prologue: W(0), X(0), W(1), X(1) issued; wait all but [W(1),X(1)]'s youngest 6
    stageW(0, 0);
    stageX(0, 0);
    stageW(64, 1);
    stageX(64, 1);
    PIPE_WAIT(6);   // W(0), X(0) landed; W(1), X(1) in flight

#pragma unroll
    for (int tt = 0; tt < 16; ++tt) {
        if (tt >= 1 && tt + 1 < 16) stageW((tt + 1) * 64, (tt + 1) & 1);
        if (tt + 2 < 16) stageX((tt + 2) * 64, (tt + 2) % 3);
        compute(&Wl[tt & 1][0], &Xl[tt % 3][0]);
        if (tt < 14)       PIPE_WAIT(4);
        else if (tt == 14) PIPE_WAIT(0);
        // tt == 15: no wait; fall through to epilogue
    }

    // epilogue: lane-local RoPE + vectorized scatter to [B,H,S,DK]
    const int h = (((int)blockIdx.x & 7) << 1) + wd;   // head index
#pragma unroll
    for (int fj = 0; fj < 4; ++fj) {
        const int rowg = s0 + wq * 64 + fj * 16 + lm;  // global token row
        const int b = rowg >> 11, ss = rowg & 2047;
        const size_t obase = ((size_t)(b * NH + h) * SEQ + ss) * DK;
        int p = 0;
        if (which < 2) p = tokpos[rowg];
#pragma unroll
        for (int fi = 0; fi < 4; ++fi) {
            const int dloc = fi * 16 + lg * 4;   // within-head d, multiple of 4
            f32x4 a = acc[fi][fj];
            bf16x4 v4;
            if (which < 2) {
                const int k2 = dloc >> 1;
                float2 cs0 = csT[p * 32 + k2];
                float2 cs1 = csT[p * 32 + k2 + 1];
                v4[0] = (bf16)(a[0] * cs0.x - a[1] * cs0.y);
                v4[1] = (bf16)(a[0] * cs0.y + a[1] * cs0.x);
                v4[2] = (bf16)(a[2] * cs1.x - a[3] * cs1.y);
                v4[3] = (bf16)(a[2] * cs1.y + a[3] * cs1.x);
            } else {
                v4[0] = (bf16)a[0]; v4[1] = (bf16)a[1];
                v4[2] = (bf16)a[2]; v4[3] = (bf16)a[3];
            }
            *reinterpret_cast<bf16x4*>(Out + obase + dloc) = v4;
        }
    }
}

// ---------------- V transpose [B,H,S,DK] -> [B,H,DK,S], sigma-permuted kv order ----
__global__ void vtrans(const bf16* __restrict__ Vb, bf16* __restrict__ Vt) {
    __shared__ ushortT tile[64][66];
    int bh = blockIdx.y, st = blockIdx.x;
    int t = threadIdx.x;
    int r = t >> 2, c4 = (t & 3) * 16;
    const ushortT* src = (const ushortT*)(Vb + ((size_t)bh * SEQ + st * 64 + r) * DK + c4);
    *reinterpret_cast<ushort8*>(&tile[r][c4]) = *reinterpret_cast<const ushort8*>(src);
    *reinterpret_cast<ushort8*>(&tile[r][c4 + 8]) = *reinterpret_cast<const ushort8*>(src + 8);
    __syncthreads();
    ushortT a[16];
#pragma unroll
    for (int i = 0; i < 16; ++i) a[i] = tile[c4 + i][r];
    ushort8 n0, n1;
#pragma unroll
    for (int i = 0; i < 4; ++i) {
        n0[i] = a[i];       n0[4 + i] = a[8 + i];
        n1[i] = a[4 + i];   n1[4 + i] = a[12 + i];
    }
    ushortT* dst = (ushortT*)(Vt + ((size_t)bh * DK + r) * SEQ + st * 64 + c4);
    *reinterpret_cast<ushort8*>(dst) = n0;
    *reinterpret_cast<ushort8*>(dst + 8) = n1;
}

// ---------------- flash attention (causal), LDS-staged K/V, 32x32 MFMA ----------------
constexpr float CL = 0.18033688011112042f;  // 0.125 * log2(e)
constexpr float THR = 64.0f;                // defer-max threshold (raw units; 8 post-scale)

template<int MODE>  // 0: chunks 0+1 unmasked; 1: chunks 0+1 masked; 2: chunk0 only, masked
DEV void tileproc(const bf16* __restrict__ Klb, const bf16* __restrict__ Vlb,
                  int kv0, int q_abs, int ql, int hi, int swq,
                  const bf16x8 qb[4], f32x16 o[2], float& lsum, float& mrow)
{
    f32x16 s0 = {}, s1 = {};
#pragma unroll
    for (int sl = 0; sl < 4; ++sl) {
        bf16x8 k0 = *reinterpret_cast<const bf16x8*>(&Klb[ql * 64 + (((sl * 2 + hi) ^ swq) * 8)]);
        s0 = __builtin_amdgcn_mfma_f32_32x32x16_bf16(k0, qb[sl], s0, 0, 0, 0);
        if (MODE != 2) {
            bf16x8 k1 = *reinterpret_cast<const bf16x8*>(&Klb[(32 + ql) * 64 + (((sl * 2 + hi) ^ swq) * 8)]);
            s1 = __builtin_amdgcn_mfma_f32_32x32x16_bf16(k1, qb[sl], s1, 0, 0, 0);
        }
    }

    if (MODE >= 1) {
#pragma unroll
        for (int r = 0; r < 16; ++r) {
            const int kvl = (r & 3) + 8 * (r >> 2) + 4 * hi;
            if (kv0 + kvl > q_abs) s0[r] = -1e30f;
            if (MODE == 1 && kv0 + 32 + kvl > q_abs) s1[r] = -1e30f;
        }
    }

    f32x16 mm = s0;
    if (MODE != 2) {
#pragma unroll
        for (int r = 0; r < 16; ++r) mm[r] = fmaxf(mm[r], s1[r]);
    }
    float m0 = fmaxf(fmaxf(mm[0], mm[1]), fmaxf(mm[2], mm[3]));
    float m1 = fmaxf(fmaxf(mm[4], mm[5]), fmaxf(mm[6], mm[7]));
    float m2 = fmaxf(fmaxf(mm[8], mm[9]), fmaxf(mm[10], mm[11]));
    float m3 = fmaxf(fmaxf(mm[12], mm[13]), fmaxf(mm[14], mm[15]));
    float pmax = fmaxf(fmaxf(m0, m1), fmaxf(m2, m3));
    pmax = fmaxf(pmax, __shfl_xor(pmax, 32));

    if (!__all(pmax <= mrow + THR)) {
        const float mnew = fmaxf(mrow, pmax);
        const float alpha = __builtin_amdgcn_exp2f((mrow - mnew) * CL);
        mrow = mnew;
        lsum *= alpha;
        o[0] *= alpha;
        o[1] *= alpha;
    }

#pragma unroll
    for (int r = 0; r < 16; ++r) {
        s0[r] = __builtin_amdgcn_exp2f((s0[r] - mrow) * CL);
        if (MODE != 2) s1[r] = __builtin_amdgcn_exp2f((s1[r] - mrow) * CL);
    }
    {
        float a0 = (s0[0] + s0[1]) + (s0[2] + s0[3]);
        float a1 = (s0[4] + s0[5]) + (s0[6] + s0[7]);
        float a2 = (s0[8] + s0[9]) + (s0[10] + s0[11]);
        float a3 = (s0[12] + s0[13]) + (s0[14] + s0[15]);
        float ps = (a0 + a1) + (a2 + a3);
        if (MODE != 2) {
            float b0 = (s1[0] + s1[1]) + (s1[2] + s1[3]);
            float b1 = (s1[4] + s1[5]) + (s1[6] + s1[7]);
            float b2 = (s1[8] + s1[9]) + (s1[10] + s1[11]);
            float b3 = (s1[12] + s1[13]) + (s1[14] + s1[15]);
            ps += (b0 + b1) + (b2 + b3);
        }
        lsum += ps;
    }

#pragma unroll
    for (int c = 0; c < (MODE == 2 ? 1 : 2); ++c) {
#pragma unroll
        for (int u2 = 0; u2 < 2; ++u2) {
            const int u = c * 2 + u2;
            bf16x8 pb;
#pragma unroll
            for (int j = 0; j < 8; ++j) pb[j] = (bf16)(c ? s1[u2 * 8 + j] : s0[u2 * 8 + j]);
#pragma unroll
            for (int dt = 0; dt < 2; ++dt) {
                bf16x8 va = *reinterpret_cast<const bf16x8*>(
                    &Vlb[(dt * 32 + ql) * 64 + (((u * 2 + hi) ^ swq) * 8)]);
                o[dt] = __builtin_amdgcn_mfma_f32_32x32x16_bf16(va, pb, o[dt], 0, 0, 0);
            }
        }
    }
}

__global__ __launch_bounds__(256, 3) void attn(
    const bf16* __restrict__ Qb, const bf16* __restrict__ Kb, const bf16* __restrict__ Vt,
    bf16* __restrict__ Ab)
{
    __shared__ bf16 Kl[2][64 * 64];
    __shared__ bf16 Vl[2][64 * 64];

    const int bh = blockIdx.x;
    const int qt = (int)gridDim.y - 1 - (int)blockIdx.y;   // longest tiles launch first (LPT)
    const int t = threadIdx.x, w = t >> 6, l = t & 63;
    const int ql = l & 31, hi = l >> 5;
    const int q0 = qt * 128 + w * 32;
    const bf16* Qh = Qb + (size_t)bh * SEQ * DK;
    const bf16* Kh = Kb + (size_t)bh * SEQ * DK;
    const bf16* Vh = Vt + (size_t)bh * DK * SEQ;

    const int lr = l >> 3, slot = l & 7;
    const int sw8 = ((slot ^ lr) * 8);
    const int r0 = w * 8 + lr;

    auto stage = [&](int tile, int buf) {
        const int kv0 = tile * 64;
        GLOAD_LDS16(Kh + (size_t)(kv0 + r0) * DK + sw8,       &Kl[buf][w * 512]);
        GLOAD_LDS16(Kh + (size_t)(kv0 + 32 + r0) * DK + sw8,  &Kl[buf][2048 + w * 512]);
        GLOAD_LDS16(Vh + (size_t)r0 * SEQ + kv0 + sw8,        &Vl[buf][w * 512]);
        GLOAD_LDS16(Vh + (size_t)(32 + r0) * SEQ + kv0 + sw8, &Vl[buf][2048 + w * 512]);
    };

    bf16x8 qb[4];
#pragma unroll
    for (int sl = 0; sl < 4; ++sl)
        qb[sl] = *reinterpret_cast<const bf16x8*>(Qh + (size_t)(q0 + ql) * DK + sl * 16 + hi * 8);

    f32x16 o[2] = {};
    float lsum = 0.0f;
    float mrow = -1e30f;
    const int q_abs = q0 + ql;
    const int swq = ql & 7;

    const int ntile = 2 * qt + 2;
    stage(0, 0);
    __syncthreads();
    for (int tt = 0; tt < ntile; ++tt) {
        if (tt + 1 < ntile) stage(tt + 1, (tt + 1) & 1);
        const int kv0 = tt * 64;
        const bf16* Klb = &Kl[tt & 1][0];
        const bf16* Vlb = &Vl[tt & 1][0];
        if (tt < 2 * qt) {
            tileproc<0>(Klb, Vlb, kv0, q_abs, ql, hi, swq, qb, o, lsum, mrow);
        } else {
            const bool a0 = kv0 <= q0 + 31;
            const bool a1 = kv0 + 32 <= q0 + 31;
            if (a1)      tileproc<1>(Klb, Vlb, kv0, q_abs, ql, hi, swq, qb, o, lsum, mrow);
            else if (a0) tileproc<2>(Klb, Vlb, kv0, q_abs, ql, hi, swq, qb, o, lsum, mrow);
        }
        __syncthreads();
    }

    const float rs = lsum + __shfl_xor(lsum, 32);
    const float rinv = 1.0f / rs;

    const int b = bh >> 4, h = bh & 15;
    const int q = q0 + ql;
    const size_t rowbase = ((size_t)(b * SEQ + q)) * DMODEL + h * 64;
#pragma unroll
    for (int dt = 0; dt < 2; ++dt)
#pragma unroll
        for (int g = 0; g < 4; ++g) {
            bf16x4 v4;
#pragma unroll
            for (int e = 0; e < 4; ++e) v4[e] = (bf16)(o[dt][4 * g + e] * rinv);
            *reinterpret_cast<bf16x4*>(Ab + rowbase + dt * 32 + 8 * g + 4 * hi) = v4;
        }
}

// ---------------- output GEMM (C^T = Wo Ab^T), same 8-wave pipelined structure ------
__global__ __launch_bounds__(512, 2) void gemm_out(
    const bf16* __restrict__ Ab, const bf16* __restrict__ Wob, float* __restrict__ Out)
{
    __shared__ bf16 Wl[2][128 * 64];
    __shared__ bf16 Xl[3][256 * 64];

    const int n0 = (int)blockIdx.x * 128;   // output-channel tile
    const int s0 = (int)blockIdx.y * 256;   // token-row tile
    const int t = threadIdx.x;
    const int w = t >> 6, l = t & 63;
    const int wd = w >> 2, wq = w & 3;
    const int lm = l & 15, lg = l >> 4;
    const int lm7 = lm & 7;

    f32x4 acc[4][4] = {};   // [fi (n)][fj (s)]

    auto stageW = [&](int kt, int buf) {
#pragma unroll
        for (int j = 0; j < 2; ++j) {
            const int slot = w * 64 + j * 512 + l;
            const int row = slot >> 3;
            const int col = ((slot & 7) ^ (row & 7)) * 8;
            GLOAD_LDS16(Wob + (size_t)(n0 + row) * KDIM + kt + col,
                        &Wl[buf][(w * 64 + j * 512) * 8]);
        }
    };
    auto stageX = [&](int kt, int buf) {
#pragma unroll
        for (int j = 0; j < 4; ++j) {
            const int slot = w * 64 + j * 512 + l;
            const int row = slot >> 3;
            const int col = ((slot & 7) ^ (row & 7)) * 8;
            GLOAD_LDS16(Ab + (size_t)(s0 + row) * KDIM + kt + col,
                        &Xl[buf][(w * 64 + j * 512) * 8]);
        }
    };
    auto compute = [&](const bf16* Wb, const bf16* Xq) {
        bf16x8 wf[4][2], xf[4][2];
#pragma unroll
        for (int fi = 0; fi < 4; ++fi) {
            const int row = wd * 64 + fi * 16 + lm;
#pragma unroll
            for (int kk = 0; kk < 2; ++kk)
                wf[fi][kk] = *reinterpret_cast<const bf16x8*>(
                    Wb + row * 64 + (((kk * 4 + lg) ^ lm7) * 8));
        }
#pragma unroll
        for (int fj = 0; fj < 4; ++fj) {
            const int row = wq * 64 + fj * 16 + lm;
#pragma unroll
            for (int kk = 0; kk < 2; ++kk)
                xf[fj][kk] = *reinterpret_cast<const bf16x8*>(
                    Xq + row * 64 + (((kk * 4 + lg) ^ lm7) * 8));
        }
        __builtin_amdgcn_s_setprio(1);
#pragma unroll
        for (int kk = 0; kk < 2; ++kk)
#pragma unroll
            for (int fi = 0; fi < 4; ++fi)
#pragma unroll
                for (int fj = 0; fj < 4; ++fj)
                    acc[fi][fj] = __builtin_amdgcn_mfma_f32_16x16x32_bf16(
                        wf[fi][kk], xf[fj][kk], acc[fi][fj], 0, 0, 0);
        __builtin_amdgcn_s_setprio(0);
    };

    stageW(0, 0);
    stageX(0, 0);
    stageW(64, 1);
    stageX(64, 1);
    PIPE_WAIT(6);

#pragma unroll
    for (int tt = 0; tt < 16; ++tt) {
        if (tt >= 1 && tt + 1 < 16) stageW((tt + 1) * 64, (tt + 1) & 1);
        if (tt + 2 < 16) stageX((tt + 2) * 64, (tt + 2) % 3);
        compute(&Wl[tt & 1][0], &Xl[tt % 3][0]);
        if (tt < 14)       PIPE_WAIT(4);
        else if (tt == 14) PIPE_WAIT(0);
    }

#pragma unroll
    for (int fj = 0; fj < 4; ++fj) {
        const int rowg = s0 + wq * 64 + fj * 16 + lm;
#pragma unroll
        for (int fi = 0; fi < 4; ++fi) {
            const int ncol = n0 + wd * 64 + fi * 16 + lg * 4;
            *reinterpret_cast<f32x4*>(Out + (size_t)rowg * DMODEL + ncol) = acc[fi][fj];
        }
    }
}

// ---------------- launch ----------------
extern "C" void kernel_launch(void* const* d_in, const int* in_sizes, int n_in,
                              void* d_out, int out_size, void* d_ws, size_t ws_size,
                              hipStream_t stream) {
    const float* X  = (const float*)d_in[0];
    const int* tokpos = (const int*)d_in[1];
    const float* Wq = (const float*)d_in[2];
    const float* Wk = (const float*)d_in[3];
    const float* Wv = (const float*)d_in[4];
    const float* Wo = (const float*)d_in[5];

    char* ws = (char*)d_ws;
    bf16* Xb  = (bf16*)(ws + 0);            // 16 MB
    bf16* Wqb = (bf16*)(ws + 16777216);     // 2 MB
    bf16* Wkb = (bf16*)(ws + 18874368);
    bf16* Wvb = (bf16*)(ws + 20971520);
    bf16* Wob = (bf16*)(ws + 23068672);
    float2* csT = (float2*)(ws + 25165824); // 512 KB interleaved (cos,sin)
    bf16* Qb = (bf16*)(ws + 25690112);      // 16 MB
    bf16* Kb = (bf16*)(ws + 42467328);
    bf16* Vb = (bf16*)(ws + 59244544);
    bf16* Vt = (bf16*)(ws + 76021760);
    bf16* Ab = (bf16*)(ws + 92798976);      // ends at 109,576,192

    cvt_bf16<<<4096, 256, 0, stream>>>(X, Xb, MROWS * DMODEL);
    cvt_bf16_w<<<dim3(512, 4), 256, 0, stream>>>(Wq, Wk, Wv, Wo, Wqb, Wkb, Wvb, Wob);
    rope_tab<<<256, 256, 0, stream>>>(csT);

    gemm_qkv<<<dim3(24, 32), 512, 0, stream>>>(
        Xb, Wqb, Wkb, Wvb, Qb, Kb, Vb, tokpos, csT);

    vtrans<<<dim3(SEQ / 64, BATCH * NH), 256, 0, stream>>>(Vb, Vt);

    attn<<<dim3(BATCH * NH, SEQ / 128), 256, 0, stream>>>(Qb, Kb, Vt, Ab);

    gemm_out<<<dim3(8, 32), 512, 0, stream>>>(Ab, Wob, (float*)d_out);
}

// Round 12
// 180.663 us; speedup vs baseline: 1.1132x; 1.0301x over previous
//
#include <hip/hip_runtime.h>
#include <hip/hip_bf16.h>

typedef __bf16 bf16;
typedef bf16 bf16x8 __attribute__((ext_vector_type(8)));
typedef bf16 bf16x4 __attribute__((ext_vector_type(4)));
typedef float f32x4 __attribute__((ext_vector_type(4)));
typedef float f32x16 __attribute__((ext_vector_type(16)));
typedef unsigned short ushortT;
typedef ushortT ushort8 __attribute__((ext_vector_type(8)));

#define DEV __device__ __forceinline__

constexpr int DMODEL = 1024;
constexpr int NH = 16;
constexpr int DK = 64;
constexpr int SEQ = 2048;
constexpr int BATCH = 4;
constexpr int MROWS = BATCH * SEQ;   // 8192
constexpr int KDIM = 1024;

#define GLOAD_LDS16(g, l) __builtin_amdgcn_global_load_lds( \
    (const __attribute__((address_space(1))) void*)(g), \
    (__attribute__((address_space(3))) void*)(l), 16, 0, 0)

#define PIPE_WAIT(N) do { \
    __builtin_amdgcn_sched_barrier(0); \
    asm volatile("s_waitcnt vmcnt(" #N ")" ::: "memory"); \
    __builtin_amdgcn_s_barrier(); \
    __builtin_amdgcn_sched_barrier(0); \
} while (0)

// ---------------- f32 -> bf16 conversion ----------------
__global__ void cvt_bf16(const float* __restrict__ src, bf16* __restrict__ dst, int n) {
    int i = (blockIdx.x * blockDim.x + threadIdx.x) * 8;
    if (i >= n) return;
    float4 f0 = *reinterpret_cast<const float4*>(src + i);
    float4 f1 = *reinterpret_cast<const float4*>(src + i + 4);
    bf16x8 o;
    o[0] = (bf16)f0.x; o[1] = (bf16)f0.y; o[2] = (bf16)f0.z; o[3] = (bf16)f0.w;
    o[4] = (bf16)f1.x; o[5] = (bf16)f1.y; o[6] = (bf16)f1.z; o[7] = (bf16)f1.w;
    *reinterpret_cast<bf16x8*>(dst + i) = o;
}

// all four weight matrices in one launch (grid.y selects)
__global__ void cvt_bf16_w(const float* __restrict__ s0, const float* __restrict__ s1,
                           const float* __restrict__ s2, const float* __restrict__ s3,
                           bf16* __restrict__ d0, bf16* __restrict__ d1,
                           bf16* __restrict__ d2, bf16* __restrict__ d3) {
    int which = blockIdx.y;
    const float* s = which == 0 ? s0 : which == 1 ? s1 : which == 2 ? s2 : s3;
    bf16* d = which == 0 ? d0 : which == 1 ? d1 : which == 2 ? d2 : d3;
    int i = (blockIdx.x * blockDim.x + threadIdx.x) * 8;
    float4 f0 = *reinterpret_cast<const float4*>(s + i);
    float4 f1 = *reinterpret_cast<const float4*>(s + i + 4);
    bf16x8 o;
    o[0] = (bf16)f0.x; o[1] = (bf16)f0.y; o[2] = (bf16)f0.z; o[3] = (bf16)f0.w;
    o[4] = (bf16)f1.x; o[5] = (bf16)f1.y; o[6] = (bf16)f1.z; o[7] = (bf16)f1.w;
    *reinterpret_cast<bf16x8*>(d + i) = o;
}

// ---------------- RoPE table: interleaved (cos,sin) pairs ----------------
__global__ void rope_tab(float2* __restrict__ csT) {
    int i = blockIdx.x * blockDim.x + threadIdx.x;  // [0, 2048*32)
    int p = i >> 5, k = i & 31;
    float inv = powf(10000.0f, -2.0f * (float)k / 64.0f);
    float ang = (float)p * inv;
    csT[i] = make_float2(cosf(ang), sinf(ang));
}

// ---------------- QKV GEMM (C^T = W X^T), 8-wave 128d x 256s tile, BK=64 ----------
// Counted-vmcnt pipeline (W 2-buf staged 1 ahead, X 3-buf staged 2 ahead).
// T1: XCD-contiguous block swizzle — each XCD owns 4 consecutive s-tiles x all 24
// (which,d) tiles, so the shared X-tiles stay resident in that XCD's L2.
__global__ __launch_bounds__(512, 2) void gemm_qkv(
    const bf16* __restrict__ Xb,
    const bf16* __restrict__ Wqb, const bf16* __restrict__ Wkb, const bf16* __restrict__ Wvb,
    bf16* __restrict__ Qb, bf16* __restrict__ Kb, bf16* __restrict__ Vb,
    const int* __restrict__ tokpos, const float2* __restrict__ csT)
{
    __shared__ bf16 Wl[2][128 * 64];   // 2 x 16KB
    __shared__ bf16 Xl[3][256 * 64];   // 3 x 32KB  (total 128KB)

    // T1 bijective swizzle: 768 blocks = 8 XCDs x 96
    const int bid = (int)blockIdx.x;
    const int swz = (bid & 7) * 96 + (bid >> 3);
    const int ytile = swz / 24;          // s-tile 0..31
    const int xtile = swz % 24;          // (which,d) 0..23

    const int which = xtile >> 3;
    const bf16* Wmat = which == 0 ? Wqb : (which == 1 ? Wkb : Wvb);
    bf16* Out = which == 0 ? Qb : (which == 1 ? Kb : Vb);

    const int d0 = (xtile & 7) * 128;    // d-tile within 1024
    const int s0 = ytile * 256;          // token-row tile
    const int t = threadIdx.x;           // 0..511
    const int w = t >> 6, l = t & 63;
    const int wd = w >> 2, wq = w & 3;   // wave quadrant: d-half, s-quarter
    const int lm = l & 15, lg = l >> 4;
    const int lm7 = lm & 7;

    f32x4 acc[4][4] = {};   // [fi (d)][fj (s)]

    auto stageW = [&](int kt, int buf) {
#pragma unroll
        for (int j = 0; j < 2; ++j) {
            const int slot = w * 64 + j * 512 + l;   // per-lane, for source addr
            const int row = slot >> 3;
            const int col = ((slot & 7) ^ (row & 7)) * 8;
            GLOAD_LDS16(Wmat + (size_t)(d0 + row) * KDIM + kt + col,
                        &Wl[buf][(w * 64 + j * 512) * 8]);   // wave-uniform dest
        }
    };
    auto stageX = [&](int kt, int buf) {
#pragma unroll
        for (int j = 0; j < 4; ++j) {
            const int slot = w * 64 + j * 512 + l;
            const int row = slot >> 3;
            const int col = ((slot & 7) ^ (row & 7)) * 8;
            GLOAD_LDS16(Xb + (size_t)(s0 + row) * KDIM + kt + col,
                        &Xl[buf][(w * 64 + j * 512) * 8]);
        }
    };
    auto compute = [&](const bf16* Wb, const bf16* Xq) {
        bf16x8 wf[4][2], xf[4][2];
#pragma unroll
        for (int fi = 0; fi < 4; ++fi) {
            const int row = wd * 64 + fi * 16 + lm;
#pragma unroll
            for (int kk = 0; kk < 2; ++kk)
                wf[fi][kk] = *reinterpret_cast<const bf16x8*>(
                    Wb + row * 64 + (((kk * 4 + lg) ^ lm7) * 8));
        }
#pragma unroll
        for (int fj = 0; fj < 4; ++fj) {
            const int row = wq * 64 + fj * 16 + lm;
#pragma unroll
            for (int kk = 0; kk < 2; ++kk)
                xf[fj][kk] = *reinterpret_cast<const bf16x8*>(
                    Xq + row * 64 + (((kk * 4 + lg) ^ lm7) * 8));
        }
        __builtin_amdgcn_s_setprio(1);
#pragma unroll
        for (int kk = 0; kk < 2; ++kk)
#pragma unroll
            for (int fi = 0; fi < 4; ++fi)
#pragma unroll
                for (int fj = 0; fj < 4; ++fj)
                    acc[fi][fj] = __builtin_amdgcn_mfma_f32_16x16x32_bf16(
                        wf[fi][kk], xf[fj][kk], acc[fi][fj], 0, 0, 0);
        __builtin_amdgcn_s_setprio(0);
    };

    // prologue: W(0), X(0), W(1), X(1) issued; wait all but [W(1),X(1)]'s 6
    stageW(0, 0);
    stageX(0, 0);
    stageW(64, 1);
    stageX(64, 1);
    PIPE_WAIT(6);   // W(0), X(0) landed; W(1), X(1) in flight

#pragma unroll
    for (int tt = 0; tt < 16; ++tt) {
        if (tt >= 1 && tt + 1 < 16) stageW((tt + 1) * 64, (tt + 1) & 1);
        if (tt + 2 < 16) stageX((tt + 2) * 64, (tt + 2) % 3);
        compute(&Wl[tt & 1][0], &Xl[tt % 3][0]);
        if (tt < 14)       PIPE_WAIT(4);
        else if (tt == 14) PIPE_WAIT(0);
        // tt == 15: no wait; fall through to epilogue
    }

    // epilogue: lane-local RoPE + vectorized scatter to [B,H,S,DK]
    const int h = ((xtile & 7) << 1) + wd;   // head index
#pragma unroll
    for (int fj = 0; fj < 4; ++fj) {
        const int rowg = s0 + wq * 64 + fj * 16 + lm;  // global token row
        const int b = rowg >> 11, ss = rowg & 2047;
        const size_t obase = ((size_t)(b * NH + h) * SEQ + ss) * DK;
        int p = 0;
        if (which < 2) p = tokpos[rowg];
#pragma unroll
        for (int fi = 0; fi < 4; ++fi) {
            const int dloc = fi * 16 + lg * 4;   // within-head d, multiple of 4
            f32x4 a = acc[fi][fj];
            bf16x4 v4;
            if (which < 2) {
                const int k2 = dloc >> 1;
                float2 cs0 = csT[p * 32 + k2];
                float2 cs1 = csT[p * 32 + k2 + 1];
                v4[0] = (bf16)(a[0] * cs0.x - a[1] * cs0.y);
                v4[1] = (bf16)(a[0] * cs0.y + a[1] * cs0.x);
                v4[2] = (bf16)(a[2] * cs1.x - a[3] * cs1.y);
                v4[3] = (bf16)(a[2] * cs1.y + a[3] * cs1.x);
            } else {
                v4[0] = (bf16)a[0]; v4[1] = (bf16)a[1];
                v4[2] = (bf16)a[2]; v4[3] = (bf16)a[3];
            }
            *reinterpret_cast<bf16x4*>(Out + obase + dloc) = v4;
        }
    }
}

// ---------------- V transpose [B,H,S,DK] -> [B,H,DK,S], sigma-permuted kv order ----
__global__ void vtrans(const bf16* __restrict__ Vb, bf16* __restrict__ Vt) {
    __shared__ ushortT tile[64][66];
    int bh = blockIdx.y, st = blockIdx.x;
    int t = threadIdx.x;
    int r = t >> 2, c4 = (t & 3) * 16;
    const ushortT* src = (const ushortT*)(Vb + ((size_t)bh * SEQ + st * 64 + r) * DK + c4);
    *reinterpret_cast<ushort8*>(&tile[r][c4]) = *reinterpret_cast<const ushort8*>(src);
    *reinterpret_cast<ushort8*>(&tile[r][c4 + 8]) = *reinterpret_cast<const ushort8*>(src + 8);
    __syncthreads();
    ushortT a[16];
#pragma unroll
    for (int i = 0; i < 16; ++i) a[i] = tile[c4 + i][r];
    ushort8 n0, n1;
#pragma unroll
    for (int i = 0; i < 4; ++i) {
        n0[i] = a[i];       n0[4 + i] = a[8 + i];
        n1[i] = a[4 + i];   n1[4 + i] = a[12 + i];
    }
    ushortT* dst = (ushortT*)(Vt + ((size_t)bh * DK + r) * SEQ + st * 64 + c4);
    *reinterpret_cast<ushort8*>(dst) = n0;
    *reinterpret_cast<ushort8*>(dst + 8) = n1;
}

// ---------------- flash attention (causal), LDS-staged K/V, 32x32 MFMA ----------------
constexpr float CL = 0.18033688011112042f;  // 0.125 * log2(e)
constexpr float THR = 64.0f;                // defer-max threshold (raw units; 8 post-scale)

template<int MODE>  // 0: chunks 0+1 unmasked; 1: chunks 0+1 masked; 2: chunk0 only, masked
DEV void tileproc(const bf16* __restrict__ Klb, const bf16* __restrict__ Vlb,
                  int kv0, int q_abs, int ql, int hi, int swq,
                  const bf16x8 qb[4], f32x16 o[2], float& lsum, float& mrow)
{
    f32x16 s0 = {}, s1 = {};
#pragma unroll
    for (int sl = 0; sl < 4; ++sl) {
        bf16x8 k0 = *reinterpret_cast<const bf16x8*>(&Klb[ql * 64 + (((sl * 2 + hi) ^ swq) * 8)]);
        s0 = __builtin_amdgcn_mfma_f32_32x32x16_bf16(k0, qb[sl], s0, 0, 0, 0);
        if (MODE != 2) {
            bf16x8 k1 = *reinterpret_cast<const bf16x8*>(&Klb[(32 + ql) * 64 + (((sl * 2 + hi) ^ swq) * 8)]);
            s1 = __builtin_amdgcn_mfma_f32_32x32x16_bf16(k1, qb[sl], s1, 0, 0, 0);
        }
    }

    if (MODE >= 1) {
#pragma unroll
        for (int r = 0; r < 16; ++r) {
            const int kvl = (r & 3) + 8 * (r >> 2) + 4 * hi;
            if (kv0 + kvl > q_abs) s0[r] = -1e30f;
            if (MODE == 1 && kv0 + 32 + kvl > q_abs) s1[r] = -1e30f;
        }
    }

    f32x16 mm = s0;
    if (MODE != 2) {
#pragma unroll
        for (int r = 0; r < 16; ++r) mm[r] = fmaxf(mm[r], s1[r]);
    }
    float m0 = fmaxf(fmaxf(mm[0], mm[1]), fmaxf(mm[2], mm[3]));
    float m1 = fmaxf(fmaxf(mm[4], mm[5]), fmaxf(mm[6], mm[7]));
    float m2 = fmaxf(fmaxf(mm[8], mm[9]), fmaxf(mm[10], mm[11]));
    float m3 = fmaxf(fmaxf(mm[12], mm[13]), fmaxf(mm[14], mm[15]));
    float pmax = fmaxf(fmaxf(m0, m1), fmaxf(m2, m3));
    pmax = fmaxf(pmax, __shfl_xor(pmax, 32));

    if (!__all(pmax <= mrow + THR)) {
        const float mnew = fmaxf(mrow, pmax);
        const float alpha = __builtin_amdgcn_exp2f((mrow - mnew) * CL);
        mrow = mnew;
        lsum *= alpha;
        o[0] *= alpha;
        o[1] *= alpha;
    }

#pragma unroll
    for (int r = 0; r < 16; ++r) {
        s0[r] = __builtin_amdgcn_exp2f((s0[r] - mrow) * CL);
        if (MODE != 2) s1[r] = __builtin_amdgcn_exp2f((s1[r] - mrow) * CL);
    }
    {
        float a0 = (s0[0] + s0[1]) + (s0[2] + s0[3]);
        float a1 = (s0[4] + s0[5]) + (s0[6] + s0[7]);
        float a2 = (s0[8] + s0[9]) + (s0[10] + s0[11]);
        float a3 = (s0[12] + s0[13]) + (s0[14] + s0[15]);
        float ps = (a0 + a1) + (a2 + a3);
        if (MODE != 2) {
            float b0 = (s1[0] + s1[1]) + (s1[2] + s1[3]);
            float b1 = (s1[4] + s1[5]) + (s1[6] + s1[7]);
            float b2 = (s1[8] + s1[9]) + (s1[10] + s1[11]);
            float b3 = (s1[12] + s1[13]) + (s1[14] + s1[15]);
            ps += (b0 + b1) + (b2 + b3);
        }
        lsum += ps;
    }

#pragma unroll
    for (int c = 0; c < (MODE == 2 ? 1 : 2); ++c) {
#pragma unroll
        for (int u2 = 0; u2 < 2; ++u2) {
            const int u = c * 2 + u2;
            bf16x8 pb;
#pragma unroll
            for (int j = 0; j < 8; ++j) pb[j] = (bf16)(c ? s1[u2 * 8 + j] : s0[u2 * 8 + j]);
#pragma unroll
            for (int dt = 0; dt < 2; ++dt) {
                bf16x8 va = *reinterpret_cast<const bf16x8*>(
                    &Vlb[(dt * 32 + ql) * 64 + (((u * 2 + hi) ^ swq) * 8)]);
                o[dt] = __builtin_amdgcn_mfma_f32_32x32x16_bf16(va, pb, o[dt], 0, 0, 0);
            }
        }
    }
}

__global__ __launch_bounds__(256, 3) void attn(
    const bf16* __restrict__ Qb, const bf16* __restrict__ Kb, const bf16* __restrict__ Vt,
    bf16* __restrict__ Ab)
{
    __shared__ bf16 Kl[2][64 * 64];
    __shared__ bf16 Vl[2][64 * 64];

    const int bh = blockIdx.x;
    const int qt = (int)gridDim.y - 1 - (int)blockIdx.y;   // longest tiles launch first (LPT)
    const int t = threadIdx.x, w = t >> 6, l = t & 63;
    const int ql = l & 31, hi = l >> 5;
    const int q0 = qt * 128 + w * 32;
    const bf16* Qh = Qb + (size_t)bh * SEQ * DK;
    const bf16* Kh = Kb + (size_t)bh * SEQ * DK;
    const bf16* Vh = Vt + (size_t)bh * DK * SEQ;

    const int lr = l >> 3, slot = l & 7;
    const int sw8 = ((slot ^ lr) * 8);
    const int r0 = w * 8 + lr;

    auto stage = [&](int tile, int buf) {
        const int kv0 = tile * 64;
        GLOAD_LDS16(Kh + (size_t)(kv0 + r0) * DK + sw8,       &Kl[buf][w * 512]);
        GLOAD_LDS16(Kh + (size_t)(kv0 + 32 + r0) * DK + sw8,  &Kl[buf][2048 + w * 512]);
        GLOAD_LDS16(Vh + (size_t)r0 * SEQ + kv0 + sw8,        &Vl[buf][w * 512]);
        GLOAD_LDS16(Vh + (size_t)(32 + r0) * SEQ + kv0 + sw8, &Vl[buf][2048 + w * 512]);
    };

    bf16x8 qb[4];
#pragma unroll
    for (int sl = 0; sl < 4; ++sl)
        qb[sl] = *reinterpret_cast<const bf16x8*>(Qh + (size_t)(q0 + ql) * DK + sl * 16 + hi * 8);

    f32x16 o[2] = {};
    float lsum = 0.0f;
    float mrow = -1e30f;
    const int q_abs = q0 + ql;
    const int swq = ql & 7;

    const int ntile = 2 * qt + 2;
    stage(0, 0);
    __syncthreads();
    for (int tt = 0; tt < ntile; ++tt) {
        if (tt + 1 < ntile) stage(tt + 1, (tt + 1) & 1);
        const int kv0 = tt * 64;
        const bf16* Klb = &Kl[tt & 1][0];
        const bf16* Vlb = &Vl[tt & 1][0];
        if (tt < 2 * qt) {
            tileproc<0>(Klb, Vlb, kv0, q_abs, ql, hi, swq, qb, o, lsum, mrow);
        } else {
            const bool a0 = kv0 <= q0 + 31;
            const bool a1 = kv0 + 32 <= q0 + 31;
            if (a1)      tileproc<1>(Klb, Vlb, kv0, q_abs, ql, hi, swq, qb, o, lsum, mrow);
            else if (a0) tileproc<2>(Klb, Vlb, kv0, q_abs, ql, hi, swq, qb, o, lsum, mrow);
        }
        __syncthreads();
    }

    const float rs = lsum + __shfl_xor(lsum, 32);
    const float rinv = 1.0f / rs;

    const int b = bh >> 4, h = bh & 15;
    const int q = q0 + ql;
    const size_t rowbase = ((size_t)(b * SEQ + q)) * DMODEL + h * 64;
#pragma unroll
    for (int dt = 0; dt < 2; ++dt)
#pragma unroll
        for (int g = 0; g < 4; ++g) {
            bf16x4 v4;
#pragma unroll
            for (int e = 0; e < 4; ++e) v4[e] = (bf16)(o[dt][4 * g + e] * rinv);
            *reinterpret_cast<bf16x4*>(Ab + rowbase + dt * 32 + 8 * g + 4 * hi) = v4;
        }
}

// ---------------- output GEMM (C^T = Wo Ab^T), 8-wave pipelined + T1 swizzle ------
__global__ __launch_bounds__(512, 2) void gemm_out(
    const bf16* __restrict__ Ab, const bf16* __restrict__ Wob, float* __restrict__ Out)
{
    __shared__ bf16 Wl[2][128 * 64];
    __shared__ bf16 Xl[3][256 * 64];

    // T1 bijective swizzle: 256 blocks = 8 XCDs x 32
    const int bid = (int)blockIdx.x;
    const int swz = (bid & 7) * 32 + (bid >> 3);
    const int ytile = swz >> 3;          // s-tile 0..31
    const int xtile = swz & 7;           // n-tile 0..7

    const int n0 = xtile * 128;          // output-channel tile
    const int s0 = ytile * 256;          // token-row tile
    const int t = threadIdx.x;
    const int w = t >> 6, l = t & 63;
    const int wd = w >> 2, wq = w & 3;
    const int lm = l & 15, lg = l >> 4;
    const int lm7 = lm & 7;

    f32x4 acc[4][4] = {};   // [fi (n)][fj (s)]

    auto stageW = [&](int kt, int buf) {
#pragma unroll
        for (int j = 0; j < 2; ++j) {
            const int slot = w * 64 + j * 512 + l;
            const int row = slot >> 3;
            const int col = ((slot & 7) ^ (row & 7)) * 8;
            GLOAD_LDS16(Wob + (size_t)(n0 + row) * KDIM + kt + col,
                        &Wl[buf][(w * 64 + j * 512) * 8]);
        }
    };
    auto stageX = [&](int kt, int buf) {
#pragma unroll
        for (int j = 0; j < 4; ++j) {
            const int slot = w * 64 + j * 512 + l;
            const int row = slot >> 3;
            const int col = ((slot & 7) ^ (row & 7)) * 8;
            GLOAD_LDS16(Ab + (size_t)(s0 + row) * KDIM + kt + col,
                        &Xl[buf][(w * 64 + j * 512) * 8]);
        }
    };
    auto compute = [&](const bf16* Wb, const bf16* Xq) {
        bf16x8 wf[4][2], xf[4][2];
#pragma unroll
        for (int fi = 0; fi < 4; ++fi) {
            const int row = wd * 64 + fi * 16 + lm;
#pragma unroll
            for (int kk = 0; kk < 2; ++kk)
                wf[fi][kk] = *reinterpret_cast<const bf16x8*>(
                    Wb + row * 64 + (((kk * 4 + lg) ^ lm7) * 8));
        }
#pragma unroll
        for (int fj = 0; fj < 4; ++fj) {
            const int row = wq * 64 + fj * 16 + lm;
#pragma unroll
            for (int kk = 0; kk < 2; ++kk)
                xf[fj][kk] = *reinterpret_cast<const bf16x8*>(
                    Xq + row * 64 + (((kk * 4 + lg) ^ lm7) * 8));
        }
        __builtin_amdgcn_s_setprio(1);
#pragma unroll
        for (int kk = 0; kk < 2; ++kk)
#pragma unroll
            for (int fi = 0; fi < 4; ++fi)
#pragma unroll
                for (int fj = 0; fj < 4; ++fj)
                    acc[fi][fj] = __builtin_amdgcn_mfma_f32_16x16x32_bf16(
                        wf[fi][kk], xf[fj][kk], acc[fi][fj], 0, 0, 0);
        __builtin_amdgcn_s_setprio(0);
    };

    stageW(0, 0);
    stageX(0, 0);
    stageW(64, 1);
    stageX(64, 1);
    PIPE_WAIT(6);

#pragma unroll
    for (int tt = 0; tt < 16; ++tt) {
        if (tt >= 1 && tt + 1 < 16) stageW((tt + 1) * 64, (tt + 1) & 1);
        if (tt + 2 < 16) stageX((tt + 2) * 64, (tt + 2) % 3);
        compute(&Wl[tt & 1][0], &Xl[tt % 3][0]);
        if (tt < 14)       PIPE_WAIT(4);
        else if (tt == 14) PIPE_WAIT(0);
    }

#pragma unroll
    for (int fj = 0; fj < 4; ++fj) {
        const int rowg = s0 + wq * 64 + fj * 16 + lm;
#pragma unroll
        for (int fi = 0; fi < 4; ++fi) {
            const int ncol = n0 + wd * 64 + fi * 16 + lg * 4;
            *reinterpret_cast<f32x4*>(Out + (size_t)rowg * DMODEL + ncol) = acc[fi][fj];
        }
    }
}

// ---------------- launch ----------------
extern "C" void kernel_launch(void* const* d_in, const int* in_sizes, int n_in,
                              void* d_out, int out_size, void* d_ws, size_t ws_size,
                              hipStream_t stream) {
    const float* X  = (const float*)d_in[0];
    const int* tokpos = (const int*)d_in[1];
    const float* Wq = (const float*)d_in[2];
    const float* Wk = (const float*)d_in[3];
    const float* Wv = (const float*)d_in[4];
    const float* Wo = (const float*)d_in[5];

    char* ws = (char*)d_ws;
    bf16* Xb  = (bf16*)(ws + 0);            // 16 MB
    bf16* Wqb = (bf16*)(ws + 16777216);     // 2 MB
    bf16* Wkb = (bf16*)(ws + 18874368);
    bf16* Wvb = (bf16*)(ws + 20971520);
    bf16* Wob = (bf16*)(ws + 23068672);
    float2* csT = (float2*)(ws + 25165824); // 512 KB interleaved (cos,sin)
    bf16* Qb = (bf16*)(ws + 25690112);      // 16 MB
    bf16* Kb = (bf16*)(ws + 42467328);
    bf16* Vb = (bf16*)(ws + 59244544);
    bf16* Vt = (bf16*)(ws + 76021760);
    bf16* Ab = (bf16*)(ws + 92798976);      // ends at 109,576,192

    cvt_bf16<<<4096, 256, 0, stream>>>(X, Xb, MROWS * DMODEL);
    cvt_bf16_w<<<dim3(512, 4), 256, 0, stream>>>(Wq, Wk, Wv, Wo, Wqb, Wkb, Wvb, Wob);
    rope_tab<<<256, 256, 0, stream>>>(csT);

    gemm_qkv<<<dim3(768), 512, 0, stream>>>(
        Xb, Wqb, Wkb, Wvb, Qb, Kb, Vb, tokpos, csT);

    vtrans<<<dim3(SEQ / 64, BATCH * NH), 256, 0, stream>>>(Vb, Vt);

    attn<<<dim3(BATCH * NH, SEQ / 128), 256, 0, stream>>>(Qb, Kb, Vt, Ab);

    gemm_out<<<dim3(256), 512, 0, stream>>>(Ab, Wob, (float*)d_out);
}